// Round 1
// baseline (568.960 us; speedup 1.0000x reference)
//
#include <hip/hip_runtime.h>
#include <hip/hip_fp16.h>

// NNUE forward: out = MLP(clip(concat(Wf@w_in^T+b, Bf@w_in^T+b)))
// Big GEMM: M=8192 (white rows 0..4095, black 4096..8191), N=256, K=40960.
// Memory-bound (1.38 GB reads -> ~220us floor). fp16 MFMA, f32 accumulate.

#define FEAT 40960
#define PSTRIDE (8192ull * 256ull)

using floatx4 = __attribute__((ext_vector_type(4))) float;
using half8   = __attribute__((ext_vector_type(8))) _Float16;
using half4   = __attribute__((ext_vector_type(4))) _Float16;

// ---------------------------------------------------------------------------
// Kernel 1: C[8192,256] partial GEMM (K-split), fp16 MFMA 16x16x32.
// BM=128, BN=128, BK=64. 512 threads = 8 waves (2 M x 4 N), wave tile 64x32.
// Reg-staged f32 loads -> cvt f16 -> XOR-swizzled LDS -> MFMA.
// ---------------------------------------------------------------------------
__global__ __launch_bounds__(512, 2) void nnue_gemm(
    const float* __restrict__ white, const float* __restrict__ black,
    const float* __restrict__ w_in, float* __restrict__ P, int KS)
{
    __shared__ __align__(16) _Float16 As[2][128 * 64];
    __shared__ __align__(16) _Float16 Ws[2][128 * 64];

    const int tid  = threadIdx.x;
    const int lane = tid & 63;
    const int wave = tid >> 6;
    const int wm   = wave >> 2;   // 0..1 (M)
    const int wn   = wave & 3;    // 0..3 (N)

    const int bid = blockIdx.x;
    const int mb  = bid / (2 * KS);
    const int rem = bid % (2 * KS);
    const int ks  = rem >> 1;
    const int nb  = rem & 1;

    const float* Abase = (mb < 32)
        ? (white + (size_t)mb * 128 * FEAT)
        : (black + (size_t)(mb - 32) * 128 * FEAT);
    const float* Wbase = w_in + (size_t)nb * 128 * FEAT;

    const int kchunk = FEAT / KS;
    const int k0     = ks * kchunk;
    const int nsteps = kchunk / 64;   // 320 (KS=2) or 640 (KS=1), always even

    // --- staging geometry: tile is [128 rows][64 k] f32 = 2048 float4.
    // thread covers slots tid, tid+512, ... : c4 = tid&15 (fixed), rows +32*i.
    const int c4    = tid & 15;
    const int row0  = tid >> 4;             // 0..31
    const int swz_w = (row0 & 7) << 4;      // XOR swizzle (16B granular)

    // --- fragment geometry (mfma_f32_16x16x32_f16, m89-verified layout):
    // operand: lane reads row (lane&15), k = (lane>>4)*8 + j  (8 halves = 16B)
    // C/D:     row = (lane>>4)*4 + reg, col = lane&15
    const int frow  = lane & 15;
    const int fhi   = lane >> 4;
    const int swz_r = (frow & 7) << 4;

    floatx4 acc[4][2];
    const floatx4 zero = {0.f, 0.f, 0.f, 0.f};
#pragma unroll
    for (int m = 0; m < 4; ++m)
#pragma unroll
        for (int n = 0; n < 2; ++n) acc[m][n] = zero;

    floatx4 ra0[4], rw0[4], ra1[4], rw1[4];

    auto issue = [&](int kglob, floatx4 (&ra)[4], floatx4 (&rw)[4]) {
#pragma unroll
        for (int i = 0; i < 4; ++i) {
            const int row = row0 + 32 * i;
            ra[i] = *reinterpret_cast<const floatx4*>(Abase + (size_t)row * FEAT + kglob + c4 * 4);
            rw[i] = *reinterpret_cast<const floatx4*>(Wbase + (size_t)row * FEAT + kglob + c4 * 4);
        }
    };

    auto cvtStore = [&](int buf, floatx4 (&ra)[4], floatx4 (&rw)[4]) {
#pragma unroll
        for (int i = 0; i < 4; ++i) {
            const int row = row0 + 32 * i;
            const int off = row * 128 + ((c4 * 8) ^ swz_w);
            half4 ha, hw;
#pragma unroll
            for (int j = 0; j < 4; ++j) {
                ha[j] = (_Float16)ra[i][j];   // v_cvt_f16_f32, RNE
                hw[j] = (_Float16)rw[i][j];
            }
            *reinterpret_cast<half4*>(reinterpret_cast<char*>(&As[buf][0]) + off) = ha;
            *reinterpret_cast<half4*>(reinterpret_cast<char*>(&Ws[buf][0]) + off) = hw;
        }
    };

    auto mfmaStep = [&](int buf) {
#pragma unroll
        for (int kk = 0; kk < 2; ++kk) {
            const int kb = (kk * 64 + fhi * 16) ^ swz_r;
            half8 af[4], bf[2];
#pragma unroll
            for (int m = 0; m < 4; ++m) {
                const int r = wm * 64 + m * 16 + frow;
                af[m] = *reinterpret_cast<const half8*>(
                    reinterpret_cast<const char*>(&As[buf][0]) + r * 128 + kb);
            }
#pragma unroll
            for (int n = 0; n < 2; ++n) {
                const int r = wn * 32 + n * 16 + frow;
                bf[n] = *reinterpret_cast<const half8*>(
                    reinterpret_cast<const char*>(&Ws[buf][0]) + r * 128 + kb);
            }
#pragma unroll
            for (int m = 0; m < 4; ++m)
#pragma unroll
                for (int n = 0; n < 2; ++n)
                    acc[m][n] = __builtin_amdgcn_mfma_f32_16x16x32_f16(af[m], bf[n], acc[m][n], 0, 0, 0);
        }
    };

    issue(k0, ra0, rw0);
    for (int t = 0; t < nsteps; t += 2) {
        if (t + 1 < nsteps) issue(k0 + (t + 1) * 64, ra1, rw1);
        cvtStore(0, ra0, rw0);
        __syncthreads();
        mfmaStep(0);
        if (t + 2 < nsteps) issue(k0 + (t + 2) * 64, ra0, rw0);
        cvtStore(1, ra1, rw1);
        __syncthreads();
        mfmaStep(1);
    }

    // epilogue: partial C (pre-bias, pre-clip) to workspace
    float* Pb = P + (size_t)ks * PSTRIDE + (size_t)mb * 128 * 256 + nb * 128;
#pragma unroll
    for (int m = 0; m < 4; ++m)
#pragma unroll
        for (int n = 0; n < 2; ++n)
#pragma unroll
            for (int r = 0; r < 4; ++r) {
                const int row = wm * 64 + m * 16 + fhi * 4 + r;
                const int col = wn * 32 + n * 16 + frow;
                Pb[(size_t)row * 256 + col] = acc[m][n][r];
            }
}

// ---------------------------------------------------------------------------
// Kernel 2: reduce K-split partials + b_in + clip -> x[4096,512] (in LDS),
// then the 3 tiny layers, all in one block per 32 batch rows.
// ---------------------------------------------------------------------------
__global__ __launch_bounds__(256) void nnue_tail(
    const float* __restrict__ P, int KS,
    const float* __restrict__ b_in,
    const float* __restrict__ w_h1, const float* __restrict__ b_h1,
    const float* __restrict__ w_h2, const float* __restrict__ b_h2,
    const float* __restrict__ w_out, const float* __restrict__ b_out,
    float* __restrict__ out)
{
    __shared__ float xs[32][512];
    __shared__ float w1[32][513];   // +1 pad: kills 32-way bank conflict
    __shared__ float w2[32][33];
    __shared__ float h1[32][33];
    __shared__ float h2[32][33];
    __shared__ float wo[32];

    const int tid = threadIdx.x;
    const int b0  = blockIdx.x * 32;

    for (int i = tid; i < 32 * 512; i += 256) w1[i >> 9][i & 511] = w_h1[i];
    for (int i = tid; i < 32 * 32; i += 256)  w2[i >> 5][i & 31]  = w_h2[i];
    if (tid < 32) wo[tid] = w_out[tid];

    // phase 1: x = clip(sum_s P[s] + b_in)
    for (int i = tid; i < 32 * 512; i += 256) {
        const int r = i >> 9, c = i & 511;
        const int persp = c >> 8, n = c & 255;
        const size_t prow = (size_t)(b0 + r) + (persp ? 4096u : 0u);
        float v = 0.f;
        for (int s = 0; s < KS; ++s) v += P[(s * PSTRIDE) + prow * 256 + n];
        v += b_in[n];
        xs[r][c] = fminf(fmaxf(v, 0.f), 1.f);
    }
    __syncthreads();

    // phase 2: h1 = clip(x @ w_h1^T + b_h1)
    for (int p = tid; p < 32 * 32; p += 256) {
        const int o = p & 31, r = p >> 5;
        float a = b_h1[o];
        for (int j = 0; j < 512; ++j) a += xs[r][j] * w1[o][j];
        h1[r][o] = fminf(fmaxf(a, 0.f), 1.f);
    }
    __syncthreads();

    // phase 3: h2 = clip(h1 @ w_h2^T + b_h2)
    for (int p = tid; p < 32 * 32; p += 256) {
        const int o = p & 31, r = p >> 5;
        float a = b_h2[o];
        for (int j = 0; j < 32; ++j) a += h1[r][j] * w2[o][j];
        h2[r][o] = fminf(fmaxf(a, 0.f), 1.f);
    }
    __syncthreads();

    // phase 4: out = h2 @ w_out^T + b_out
    if (tid < 32) {
        float a = b_out[0];
        for (int j = 0; j < 32; ++j) a += h2[tid][j] * wo[j];
        out[b0 + tid] = a;
    }
}

// ---------------------------------------------------------------------------
// Emergency fallback (only if ws_size < 8 MB): slow but correct, no scratch.
// ---------------------------------------------------------------------------
__global__ __launch_bounds__(256) void nnue_naive(
    const float* __restrict__ white, const float* __restrict__ black,
    const float* __restrict__ w_in, const float* __restrict__ b_in,
    const float* __restrict__ w_h1, const float* __restrict__ b_h1,
    const float* __restrict__ w_h2, const float* __restrict__ b_h2,
    const float* __restrict__ w_out, const float* __restrict__ b_out,
    float* __restrict__ out)
{
    __shared__ float feat[4096];
    __shared__ float xs[512];
    __shared__ float h1s[32];
    __shared__ float h2s[32];
    const int b = blockIdx.x, tid = threadIdx.x;
    float acc0 = 0.f, acc1 = 0.f;
    for (int c = 0; c < FEAT; c += 2048) {
        for (int i = tid; i < 2048; i += 256) {
            feat[i]        = white[(size_t)b * FEAT + c + i];
            feat[2048 + i] = black[(size_t)b * FEAT + c + i];
        }
        __syncthreads();
        const float* wr = w_in + (size_t)tid * FEAT + c;
        for (int k = 0; k < 2048; ++k) {
            const float w = wr[k];
            acc0 += feat[k] * w;
            acc1 += feat[2048 + k] * w;
        }
        __syncthreads();
    }
    xs[tid]       = fminf(fmaxf(acc0 + b_in[tid], 0.f), 1.f);
    xs[256 + tid] = fminf(fmaxf(acc1 + b_in[tid], 0.f), 1.f);
    __syncthreads();
    if (tid < 32) {
        float a = b_h1[tid];
        for (int j = 0; j < 512; ++j) a += xs[j] * w_h1[tid * 512 + j];
        h1s[tid] = fminf(fmaxf(a, 0.f), 1.f);
    }
    __syncthreads();
    if (tid < 32) {
        float a = b_h2[tid];
        for (int j = 0; j < 32; ++j) a += h1s[j] * w_h2[tid * 32 + j];
        h2s[tid] = fminf(fmaxf(a, 0.f), 1.f);
    }
    __syncthreads();
    if (tid == 0) {
        float a = b_out[0];
        for (int j = 0; j < 32; ++j) a += h2s[j] * w_out[j];
        out[b] = a;
    }
}

extern "C" void kernel_launch(void* const* d_in, const int* in_sizes, int n_in,
                              void* d_out, int out_size, void* d_ws, size_t ws_size,
                              hipStream_t stream)
{
    const float* white = (const float*)d_in[0];
    const float* black = (const float*)d_in[1];
    const float* w_in  = (const float*)d_in[2];
    const float* b_in  = (const float*)d_in[3];
    const float* w_h1  = (const float*)d_in[4];
    const float* b_h1  = (const float*)d_in[5];
    const float* w_h2  = (const float*)d_in[6];
    const float* b_h2  = (const float*)d_in[7];
    const float* w_out = (const float*)d_in[8];
    const float* b_out = (const float*)d_in[9];
    float* out = (float*)d_out;
    float* P   = (float*)d_ws;

    const size_t bytesPerSplit = PSTRIDE * sizeof(float);   // 8 MB
    int KS;
    if (ws_size >= 2 * bytesPerSplit)      KS = 2;  // 256 blocks, 1/CU
    else if (ws_size >= bytesPerSplit)     KS = 1;  // 128 blocks
    else                                   KS = 0;  // no scratch: naive path

    if (KS == 0) {
        nnue_naive<<<4096, 256, 0, stream>>>(white, black, w_in, b_in, w_h1, b_h1,
                                             w_h2, b_h2, w_out, b_out, out);
        return;
    }

    nnue_gemm<<<dim3(64 * 2 * KS), 512, 0, stream>>>(white, black, w_in, P, KS);
    nnue_tail<<<dim3(128), 256, 0, stream>>>(P, KS, b_in, w_h1, b_h1,
                                             w_h2, b_h2, w_out, b_out, out);
}